// Round 6
// baseline (47796.982 us; speedup 1.0000x reference)
//
#include <hip/hip_runtime.h>
#include <cstdint>
#include <cstddef>

#define SEQ   8192
#define HD    2048
#define IND   16
#define NBLK  256   // one block per CU; each owns 8 hidden units
#define NTHR  256   // 4 waves; wave w owns units {b*8+2w, b*8+2w+1} = 8 rows
#define NPR   1024  // h2 pairs in h (HD/2)

typedef _Float16 h2  __attribute__((ext_vector_type(2)));
typedef unsigned u32x4 __attribute__((ext_vector_type(4)));

union paircvt { h2 v; unsigned u; };

__device__ __forceinline__ float fdot2f(h2 a, h2 b, float c) {
#if defined(__has_builtin)
#if __has_builtin(__builtin_amdgcn_fdot2)
    return __builtin_amdgcn_fdot2(a, b, c, false);
#else
    return c + (float)a.x * (float)b.x + (float)a.y * (float)b.y;
#endif
#else
    return c + (float)a.x * (float)b.x + (float)a.y * (float)b.y;
#endif
}

__device__ __forceinline__ float sigmoid_f(float x) {
    return 1.f / (1.f + __expf(-x));
}
__device__ __forceinline__ float tanh_f(float x) {
    float e = __expf(2.f * x);
    return 1.f - 2.f / (e + 1.f);
}

// Persistent LSTM, round 6: MINIMAL-TRAFFIC sync.
// R2/R3/R5 all plateau at ~7000 cyc/step; R5 counters show compute is only
// ~1300 of those. Diagnosis: every block poll-spins 8 KB of sc1 (IF-served)
// loads ~12x per step -> ~7 TB/s of Infinity-Fabric traffic hammering 16 KB,
// queueing the genuine publish/discovery ops behind it (R4 = extreme case).
// This round starves the polls:
//   - tags (256 x 4 B, one per block) separated from data (1024 x 4 B pairs)
//   - producer: data store sc1 -> vmcnt(0) -> LDS arrival counter; last wave
//     of the block stores the single block tag (data-before-tag guaranteed)
//   - ONLY wave 0 polls, tags-only (1 KB/iter), s_sleep(2) pacing; on
//     success it single-shot reads the 4 KB data (fresh: issued after tag
//     observation) and stages to LDS; waves 1-3 wait at the barrier
//   - fragments read as 4x ds_read_b128 (2-way conflicts = free)
//   - xp precomputed before the barrier (off critical path)
__global__ __launch_bounds__(NTHR, 1) void lstm_persist(
    const float* __restrict__ sa,    // [SEQ, IND]
    const float* __restrict__ W_ih,  // [4*HD, IND]
    const float* __restrict__ W_hh,  // [4*HD, HD]
    const float* __restrict__ b_ih,  // [4*HD]
    const float* __restrict__ b_hh,  // [4*HD]
    unsigned* __restrict__ hdat,     // [2][NPR]  packed h2 pairs (zeroed)
    unsigned* __restrict__ tagv,     // [2][NBLK] per-block step tags (zeroed)
    _Float16* __restrict__ hs16)     // [SEQ, HD] h history (fp16)
{
    const int b   = blockIdx.x;
    const int tid = threadIdx.x;
    const int w   = tid >> 6;        // wave 0..3
    const int L   = tid & 63;        // lane

    __shared__ u32x4   hlds4[256];   // 4 KB: h_t pairs, plain packed layout
    __shared__ unsigned cnt[2];      // per-parity arrival counters
    if (tid == 0) { cnt[0] = 0; cnt[1] = 0; }

    const int ubase = b * 8 + 2 * w; // first of this wave's 2 units

    // ---- one-time: W_hh fragment -> registers (fp16 pairs) ----
    // 8 rows (r: gate=r&3, unit=r>>2), lane L owns cols [32L, 32L+32)
    h2 wreg[8][16];
#pragma unroll
    for (int r = 0; r < 8; ++r) {
        const int row = (r & 3) * HD + ubase + (r >> 2);
        const float4* Wr = (const float4*)(W_hh + (size_t)row * HD + L * 32);
#pragma unroll
        for (int q = 0; q < 8; ++q) {
            float4 f = Wr[q];
            h2 lo; lo.x = (_Float16)f.x; lo.y = (_Float16)f.y;
            h2 hi; hi.x = (_Float16)f.z; hi.y = (_Float16)f.w;
            wreg[r][2 * q]     = lo;
            wreg[r][2 * q + 1] = hi;
        }
    }
    // W_ih row + bias for the row this lane ends up holding (r = L&7)
    const int rowL = (L & 3) * HD + ubase + ((L >> 2) & 1);
    float wih[IND];
    {
        const float4* Wi = (const float4*)(W_ih + (size_t)rowL * IND);
#pragma unroll
        for (int q = 0; q < 4; ++q) {
            float4 f = Wi[q];
            wih[4 * q]     = f.x;
            wih[4 * q + 1] = f.y;
            wih[4 * q + 2] = f.z;
            wih[4 * q + 3] = f.w;
        }
    }
    const float bias = b_ih[rowL] + b_hh[rowL];

    // cell state: lanes with (L&4)==0 hold c of unit0, (L&4)==4 -> unit1
    float c = 0.f;

    for (unsigned t = 0; t < SEQ; ++t) {
        // ---- xp precompute (h-independent): off the critical path ----
        float xp = bias;
        {
            const float* sat = sa + (size_t)t * IND;
#pragma unroll
            for (int k = 0; k < IND; ++k) xp += sat[k] * wih[k];
        }

        const unsigned pin = t & 1;
        // ---- wave 0: poll 256 tags (1 KB), then single-shot data read ----
        if (w == 0) {
            const unsigned* tp = tagv + pin * NBLK + 4 * L;
            u32x4 tg;
            for (;;) {
                asm volatile("global_load_dwordx4 %0, %1, off sc1\n\t"
                             "s_waitcnt vmcnt(0)"
                             : "=v"(tg) : "v"(tp) : "memory");
                bool ok = (tg.x == t) & (tg.y == t) & (tg.z == t) & (tg.w == t);
                if (__all(ok)) break;
                __builtin_amdgcn_s_sleep(2);
            }
            // data is guaranteed visible (store->vmcnt->tag per producer);
            // these loads are issued strictly after tag observation
            const unsigned* dp = hdat + pin * NPR + 16 * L;
            u32x4 d0, d1, d2, d3;
            asm volatile(
                "global_load_dwordx4 %0, %4, off sc1\n\t"
                "global_load_dwordx4 %1, %4, off offset:16 sc1\n\t"
                "global_load_dwordx4 %2, %4, off offset:32 sc1\n\t"
                "global_load_dwordx4 %3, %4, off offset:48 sc1\n\t"
                "s_waitcnt vmcnt(0)"
                : "=v"(d0), "=v"(d1), "=v"(d2), "=v"(d3)
                : "v"(dp) : "memory");
            hlds4[4 * L]     = d0;
            hlds4[4 * L + 1] = d1;
            hlds4[4 * L + 2] = d2;
            hlds4[4 * L + 3] = d3;
        }
        __syncthreads();

        // ---- read this lane's 16 pairs (cols [32L, 32L+32)) ----
        u32x4 r0 = hlds4[4 * L];
        u32x4 r1 = hlds4[4 * L + 1];
        u32x4 r2 = hlds4[4 * L + 2];
        u32x4 r3 = hlds4[4 * L + 3];
        h2 hv[16];
        {
            paircvt cv;
            cv.u = r0.x; hv[0]  = cv.v;  cv.u = r0.y; hv[1]  = cv.v;
            cv.u = r0.z; hv[2]  = cv.v;  cv.u = r0.w; hv[3]  = cv.v;
            cv.u = r1.x; hv[4]  = cv.v;  cv.u = r1.y; hv[5]  = cv.v;
            cv.u = r1.z; hv[6]  = cv.v;  cv.u = r1.w; hv[7]  = cv.v;
            cv.u = r2.x; hv[8]  = cv.v;  cv.u = r2.y; hv[9]  = cv.v;
            cv.u = r2.z; hv[10] = cv.v;  cv.u = r2.w; hv[11] = cv.v;
            cv.u = r3.x; hv[12] = cv.v;  cv.u = r3.y; hv[13] = cv.v;
            cv.u = r3.z; hv[14] = cv.v;  cv.u = r3.w; hv[15] = cv.v;
        }

        // ---- 8 rows x 32 cols of dot product per lane ----
        float p[8] = {0.f, 0.f, 0.f, 0.f, 0.f, 0.f, 0.f, 0.f};
#pragma unroll
        for (int r = 0; r < 8; ++r)
#pragma unroll
            for (int k = 0; k < 16; ++k)
                p[r] = fdot2f(wreg[r][k], hv[k], p[r]);

        // ---- merge-reduce: lane L ends with full sum of row (L&7) ----
        const bool h1 = (L & 1), h2b = (L & 2), h4 = (L & 4);
        float v0, v1, v2, v3;
        {
            float k0 = h1 ? p[1] : p[0], s0 = h1 ? p[0] : p[1];
            v0 = k0 + __shfl_xor(s0, 1, 64);
            float k1 = h1 ? p[3] : p[2], s1 = h1 ? p[2] : p[3];
            v1 = k1 + __shfl_xor(s1, 1, 64);
            float k2 = h1 ? p[5] : p[4], s2 = h1 ? p[4] : p[5];
            v2 = k2 + __shfl_xor(s2, 1, 64);
            float k3 = h1 ? p[7] : p[6], s3 = h1 ? p[6] : p[7];
            v3 = k3 + __shfl_xor(s3, 1, 64);
        }
        float w0, w1;
        {
            float k0 = h2b ? v1 : v0, s0 = h2b ? v0 : v1;
            w0 = k0 + __shfl_xor(s0, 2, 64);
            float k1 = h2b ? v3 : v2, s1 = h2b ? v2 : v3;
            w1 = k1 + __shfl_xor(s1, 2, 64);
        }
        float tot;
        {
            float k0 = h4 ? w1 : w0, s0 = h4 ? w0 : w1;
            tot = k0 + __shfl_xor(s0, 4, 64);
        }
        tot += __shfl_xor(tot, 8, 64);
        tot += __shfl_xor(tot, 16, 64);
        tot += __shfl_xor(tot, 32, 64);
        tot += xp;

        // ---- gates: all intra-wave (width-8 shuffles) ----
        const int ub4 = L & 4;   // 0 -> unit0 rows 0..3, 4 -> unit1 rows 4..7
        float gi = __shfl(tot, ub4 + 0, 8);
        float gf = __shfl(tot, ub4 + 1, 8);
        float gg = __shfl(tot, ub4 + 2, 8);
        float go = __shfl(tot, ub4 + 3, 8);
        float ii = sigmoid_f(gi);
        float ff = sigmoid_f(gf);
        float g  = tanh_f(gg);
        float oo = sigmoid_f(go);
        c = ff * c + ii * g;
        float h = oo * tanh_f(c);
        float hO = __shfl_xor(h, 4, 64);   // lane0: unit1's h (from lane4)

        // ---- publish: data store -> vmcnt -> arrival count -> block tag ----
        if (L == 0) {
            paircvt pk;
            pk.v.x = (_Float16)h;    // unit ubase
            pk.v.y = (_Float16)hO;   // unit ubase+1
            const unsigned pout = (t + 1) & 1;
            unsigned* dstp = hdat + pout * NPR + (b * 4 + w);
            asm volatile("global_store_dword %0, %1, off sc1\n\t"
                         "s_waitcnt vmcnt(0)"
                         :: "v"(dstp), "v"(pk.u) : "memory");
            unsigned old = atomicAdd(&cnt[pout], 1u);
            if (old == 3u) {   // last wave of this block: publish the tag
                unsigned* tgp = tagv + pout * NBLK + b;
                unsigned tv = t + 1;
                asm volatile("global_store_dword %0, %1, off sc1"
                             :: "v"(tgp), "v"(tv) : "memory");
                cnt[pout] = 0;   // reset for t+2 (safe: long causal gap)
            }
            // h history (off critical path; kernel-end flush orders it
            // before out_proj)
            ((unsigned*)hs16)[(size_t)t * (HD / 2) + b * 4 + w] = pk.u;
        }
    }
}

// Output projection: out[t,0:3] = hs[t]·W_uvw^T + b_uvw,
//                    out[t,3:6] = hs[t]·W_pqr^T + b_pqr
__global__ __launch_bounds__(256) void out_proj_kernel(
    const _Float16* __restrict__ hs16,
    const float* __restrict__ W_uvw, const float* __restrict__ b_uvw,
    const float* __restrict__ W_pqr, const float* __restrict__ b_pqr,
    float* __restrict__ out)
{
    __shared__ float Ws[6 * HD];
    const int tid = threadIdx.x;
    for (int i = tid; i < 3 * HD; i += 256) Ws[i] = W_uvw[i];
    for (int i = tid; i < 3 * HD; i += 256) Ws[3 * HD + i] = W_pqr[i];
    __syncthreads();

    const int w = tid >> 6, L = tid & 63;
#pragma unroll
    for (int r = 0; r < 4; ++r) {
        const int t = blockIdx.x * 16 + w * 4 + r;
        const _Float16* hrow = hs16 + (size_t)t * HD;
        float acc[6] = {0.f, 0.f, 0.f, 0.f, 0.f, 0.f};
        for (int cidx = L; cidx < HD; cidx += 64) {
            float hval = (float)hrow[cidx];
#pragma unroll
            for (int j = 0; j < 6; ++j) acc[j] += hval * Ws[j * HD + cidx];
        }
#pragma unroll
        for (int j = 0; j < 6; ++j) {
#pragma unroll
            for (int d = 1; d < 64; d <<= 1)
                acc[j] += __shfl_xor(acc[j], d, 64);
        }
        if (L == 0) {
#pragma unroll
            for (int j = 0; j < 6; ++j)
                out[(size_t)t * 6 + j] =
                    acc[j] + (j < 3 ? b_uvw[j] : b_pqr[j - 3]);
        }
    }
}

extern "C" void kernel_launch(void* const* d_in, const int* in_sizes, int n_in,
                              void* d_out, int out_size, void* d_ws, size_t ws_size,
                              hipStream_t stream) {
    (void)in_sizes; (void)n_in; (void)out_size; (void)ws_size;

    const float* sa    = (const float*)d_in[0];
    const float* W_ih  = (const float*)d_in[1];
    const float* W_hh  = (const float*)d_in[2];
    const float* b_ih  = (const float*)d_in[3];
    const float* b_hh  = (const float*)d_in[4];
    const float* W_uvw = (const float*)d_in[5];
    const float* b_uvw = (const float*)d_in[6];
    const float* W_pqr = (const float*)d_in[7];
    const float* b_pqr = (const float*)d_in[8];
    float* out = (float*)d_out;

    // workspace: [hs16: 32 MB][hdat: 2*NPR*4 = 8 KB][tagv: 2*NBLK*4 = 2 KB]
    char* ws = (char*)d_ws;
    _Float16* hs16 = (_Float16*)ws;
    unsigned* hdat = (unsigned*)(ws + (size_t)SEQ * HD * 2);
    unsigned* tagv = hdat + 2 * NPR;

    // zero data+tags: tag 0 == "h_0 = 0 is ready" for parity-0 buffer
    hipMemsetAsync(hdat, 0, (size_t)(2 * NPR + 2 * NBLK) * 4, stream);

    hipLaunchKernelGGL(lstm_persist, dim3(NBLK), dim3(NTHR), 0, stream,
                       sa, W_ih, W_hh, b_ih, b_hh, hdat, tagv, hs16);
    hipLaunchKernelGGL(out_proj_kernel, dim3(SEQ / 16), dim3(256), 0, stream,
                       hs16, W_uvw, b_uvw, W_pqr, b_pqr, out);
}

// Round 8
// 21526.912 us; speedup vs baseline: 2.2203x; 2.2203x over previous
//
#include <hip/hip_runtime.h>
#include <cstdint>
#include <cstddef>

#define SEQ   8192
#define HD    2048
#define IND   16
#define NWRK  256   // worker blocks; each owns 8 hidden units
#define NRLY  8     // relay blocks (blockIdx 0..7), one wave each
#define NGRID (NWRK + NRLY)
#define NTHR  256   // 4 waves; wave w owns units {wid*8+2w, wid*8+2w+1}
#define NSLOT 1024  // u64 slots per parity: lo32 = 2xfp16 h-pair, hi32 = tag
#define NXCD  8

typedef _Float16 h2  __attribute__((ext_vector_type(2)));
typedef unsigned u32x4 __attribute__((ext_vector_type(4)));

union paircvt { h2 v; unsigned u; };

__device__ __forceinline__ float fdot2f(h2 a, h2 b, float c) {
#if defined(__has_builtin)
#if __has_builtin(__builtin_amdgcn_fdot2)
    return __builtin_amdgcn_fdot2(a, b, c, false);
#else
    return c + (float)a.x * (float)b.x + (float)a.y * (float)b.y;
#endif
#else
    return c + (float)a.x * (float)b.x + (float)a.y * (float)b.y;
#endif
}

__device__ __forceinline__ float sigmoid_f(float x) {
    return 1.f / (1.f + __expf(-x));
}
__device__ __forceinline__ float tanh_f(float x) {
    float e = __expf(2.f * x);
    return 1.f - 2.f / (e + 1.f);
}

__device__ __forceinline__ unsigned my_xcd() {
    unsigned x;
    asm volatile("s_getreg_b32 %0, hwreg(HW_REG_XCC_ID, 0, 4)" : "=s"(x));
    return x & (NXCD - 1);
}

// Persistent LSTM, round 8: XCD-local polling with SAFE fallback.
// Flat sc1 polling saturates the coherence point (R2/R3/R5 ~7000 cyc/step,
// compute only ~1300). R7's relay idea was right but deadlock-prone
// (all-grid registration barrier + topology-dependent correctness). Here:
//   - blockIdx 0..7 = relays: forward the 8 KB global tagged array into
//     their OWN physical XCD's L2 mirror (plain write-back stores),
//     idempotently; no election, no barrier. Duplicate relays per XCD are
//     harmless; a missing relay is covered by the worker fallback.
//   - workers poll mirror[own_xcd] with sc0 (own-L2, no IF traffic);
//     every 4th miss they try one sc1 global read. Embedded tags make any
//     hop exact (stale relay re-stores can't fake-match: tags only grow).
//     No wait can deadlock: global sc1 is always a correct source.
//   - publishers also drop their 8B word into their local mirror (1 plain
//     store) so same-XCD consumers skip the relay hop.
// Compute path = R5 verbatim (absmax 2.44e-4, 0 LDS conflicts, 1 barrier).
__global__ __launch_bounds__(NTHR, 1) void lstm_persist(
    const float* __restrict__ sa,    // [SEQ, IND]
    const float* __restrict__ W_ih,  // [4*HD, IND]
    const float* __restrict__ W_hh,  // [4*HD, HD]
    const float* __restrict__ b_ih,  // [4*HD]
    const float* __restrict__ b_hh,  // [4*HD]
    unsigned long long* __restrict__ hmsg,  // [2][NSLOT] global tagged slots
    unsigned long long* __restrict__ mirr,  // [NXCD][2][NSLOT] L2 mirrors
    _Float16* __restrict__ hs16)     // [SEQ, HD] h history (fp16)
{
    const int tid = threadIdx.x;
    const int w   = tid >> 6;        // wave 0..3
    const int L   = tid & 63;        // lane

    // ================= RELAY BLOCKS =================
    if (blockIdx.x < NRLY) {
        if (w != 0) return;          // one wave per relay
        const unsigned x = my_xcd();
        for (unsigned t = 0; t < SEQ; ++t) {
            const unsigned pin = t & 1;
            const unsigned* gp0 =
                (const unsigned*)(hmsg + (size_t)pin * NSLOT) + 4 * L;
            const unsigned* gp1 = gp0 + 1024;   // +4096 B
            u32x4* mb = (u32x4*)(mirr + ((size_t)x * 2 + pin) * NSLOT);
            for (;;) {
                u32x4 g0, g1, g2, g3, g4, g5, g6, g7;
                asm volatile(
                    "global_load_dwordx4 %0, %8, off sc1\n\t"
                    "global_load_dwordx4 %1, %8, off offset:1024 sc1\n\t"
                    "global_load_dwordx4 %2, %8, off offset:2048 sc1\n\t"
                    "global_load_dwordx4 %3, %8, off offset:3072 sc1\n\t"
                    "global_load_dwordx4 %4, %9, off sc1\n\t"
                    "global_load_dwordx4 %5, %9, off offset:1024 sc1\n\t"
                    "global_load_dwordx4 %6, %9, off offset:2048 sc1\n\t"
                    "global_load_dwordx4 %7, %9, off offset:3072 sc1\n\t"
                    "s_waitcnt vmcnt(0)"
                    : "=v"(g0), "=v"(g1), "=v"(g2), "=v"(g3),
                      "=v"(g4), "=v"(g5), "=v"(g6), "=v"(g7)
                    : "v"(gp0), "v"(gp1) : "memory");
                // idempotent forward into own-XCD L2 (plain stores)
                mb[      L] = g0; mb[ 64 + L] = g1;
                mb[128 + L] = g2; mb[192 + L] = g3;
                mb[256 + L] = g4; mb[320 + L] = g5;
                mb[384 + L] = g6; mb[448 + L] = g7;
                bool ok = (g0.y == t) & (g0.w == t) & (g1.y == t) & (g1.w == t)
                        & (g2.y == t) & (g2.w == t) & (g3.y == t) & (g3.w == t)
                        & (g4.y == t) & (g4.w == t) & (g5.y == t) & (g5.w == t)
                        & (g6.y == t) & (g6.w == t) & (g7.y == t) & (g7.w == t);
                if (__all(ok)) break;
            }
        }
        return;
    }

    // ================= WORKER BLOCKS =================
    const int wid = blockIdx.x - NRLY;       // 0..255
    const unsigned xcd = my_xcd();
    __shared__ h2 hh2[16 * 64];              // h_t pairs, XOR-swizzled

    const int ubase = wid * 8 + 2 * w;       // first of this wave's 2 units

    // ---- one-time: W_hh fragment -> registers (fp16 pairs) ----
    h2 wreg[8][16];
#pragma unroll
    for (int r = 0; r < 8; ++r) {
        const int row = (r & 3) * HD + ubase + (r >> 2);
        const float4* Wr = (const float4*)(W_hh + (size_t)row * HD + L * 32);
#pragma unroll
        for (int q = 0; q < 8; ++q) {
            float4 f = Wr[q];
            h2 lo; lo.x = (_Float16)f.x; lo.y = (_Float16)f.y;
            h2 hi; hi.x = (_Float16)f.z; hi.y = (_Float16)f.w;
            wreg[r][2 * q]     = lo;
            wreg[r][2 * q + 1] = hi;
        }
    }
    const int rowL = (L & 3) * HD + ubase + ((L >> 2) & 1);
    float wih[IND];
    {
        const float4* Wi = (const float4*)(W_ih + (size_t)rowL * IND);
#pragma unroll
        for (int q = 0; q < 4; ++q) {
            float4 f = Wi[q];
            wih[4 * q]     = f.x;
            wih[4 * q + 1] = f.y;
            wih[4 * q + 2] = f.z;
            wih[4 * q + 3] = f.w;
        }
    }
    const float bias = b_ih[rowL] + b_hh[rowL];

    float c = 0.f;   // (L&4)==0 -> unit0, else unit1

    for (unsigned t = 0; t < SEQ; ++t) {
        // ---- xp precompute (h-independent) ----
        float xp = bias;
        {
            const float* sat = sa + (size_t)t * IND;
#pragma unroll
            for (int k = 0; k < IND; ++k) xp += sat[k] * wih[k];
        }

        const unsigned pin = t & 1;
        const uint32_t* lb =
            (const uint32_t*)(mirr + ((size_t)xcd * 2 + pin) * NSLOT);
        const uint32_t* lp0 = lb + 4 * tid;
        const uint32_t* lp1 = lb + 1024 + 4 * tid;
        const uint32_t* gb = (const uint32_t*)(hmsg + (size_t)pin * NSLOT);
        const uint32_t* gp0 = gb + 4 * tid;
        const uint32_t* gp1 = gb + 1024 + 4 * tid;

        u32x4 m0, m1;
        unsigned miss = 0;
        for (;;) {
            // fast path: own-XCD L2 mirror (sc0)
            asm volatile(
                "global_load_dwordx4 %0, %2, off sc0\n\t"
                "global_load_dwordx4 %1, %3, off sc0\n\t"
                "s_waitcnt vmcnt(0)"
                : "=v"(m0), "=v"(m1)
                : "v"(lp0), "v"(lp1) : "memory");
            if ((m0.y == t) & (m0.w == t) & (m1.y == t) & (m1.w == t)) break;
            if ((miss & 3u) == 3u) {
                // fallback: authoritative global (sc1) — always correct
                asm volatile(
                    "global_load_dwordx4 %0, %2, off sc1\n\t"
                    "global_load_dwordx4 %1, %3, off sc1\n\t"
                    "s_waitcnt vmcnt(0)"
                    : "=v"(m0), "=v"(m1)
                    : "v"(gp0), "v"(gp1) : "memory");
                if ((m0.y == t) & (m0.w == t) & (m1.y == t) & (m1.w == t))
                    break;
            }
            ++miss;
            __builtin_amdgcn_s_sleep(1);
        }

        // ---- stage 4 pairs into swizzled LDS (<=2-way = free) ----
        {
            paircvt cv;
            const int pa = 2 * tid, pb = 2 * tid + 1;
            const int pc = 512 + 2 * tid, pd = 513 + 2 * tid;
            cv.u = m0.x;
            hh2[(pa & 15) * 64 + (((pa >> 4) ^ (2 * (pa & 15))) & 63)] = cv.v;
            cv.u = m0.z;
            hh2[(pb & 15) * 64 + (((pb >> 4) ^ (2 * (pb & 15))) & 63)] = cv.v;
            cv.u = m1.x;
            hh2[(pc & 15) * 64 + (((pc >> 4) ^ (2 * (pc & 15))) & 63)] = cv.v;
            cv.u = m1.z;
            hh2[(pd & 15) * 64 + (((pd >> 4) ^ (2 * (pd & 15))) & 63)] = cv.v;
        }
        __syncthreads();

        // ---- read this lane's 16 pairs (cols [32L, 32L+32)) ----
        h2 hv[16];
#pragma unroll
        for (int k = 0; k < 16; ++k)
            hv[k] = hh2[k * 64 + ((L ^ (2 * k)) & 63)];

        // ---- 8 rows x 32 cols of dot product per lane ----
        float p[8] = {0.f, 0.f, 0.f, 0.f, 0.f, 0.f, 0.f, 0.f};
#pragma unroll
        for (int r = 0; r < 8; ++r)
#pragma unroll
            for (int k = 0; k < 16; ++k)
                p[r] = fdot2f(wreg[r][k], hv[k], p[r]);

        // ---- merge-reduce: lane L ends with full sum of row (L&7) ----
        const bool h1 = (L & 1), h2b = (L & 2), h4 = (L & 4);
        float v0, v1, v2, v3;
        {
            float k0 = h1 ? p[1] : p[0], s0 = h1 ? p[0] : p[1];
            v0 = k0 + __shfl_xor(s0, 1, 64);
            float k1 = h1 ? p[3] : p[2], s1 = h1 ? p[2] : p[3];
            v1 = k1 + __shfl_xor(s1, 1, 64);
            float k2 = h1 ? p[5] : p[4], s2 = h1 ? p[4] : p[5];
            v2 = k2 + __shfl_xor(s2, 1, 64);
            float k3 = h1 ? p[7] : p[6], s3 = h1 ? p[6] : p[7];
            v3 = k3 + __shfl_xor(s3, 1, 64);
        }
        float w0, w1;
        {
            float k0 = h2b ? v1 : v0, s0 = h2b ? v0 : v1;
            w0 = k0 + __shfl_xor(s0, 2, 64);
            float k1 = h2b ? v3 : v2, s1 = h2b ? v2 : v3;
            w1 = k1 + __shfl_xor(s1, 2, 64);
        }
        float tot;
        {
            float k0 = h4 ? w1 : w0, s0 = h4 ? w0 : w1;
            tot = k0 + __shfl_xor(s0, 4, 64);
        }
        tot += __shfl_xor(tot, 8, 64);
        tot += __shfl_xor(tot, 16, 64);
        tot += __shfl_xor(tot, 32, 64);
        tot += xp;

        // ---- gates: all intra-wave (width-8 shuffles) ----
        const int ub4 = L & 4;
        float gi = __shfl(tot, ub4 + 0, 8);
        float gf = __shfl(tot, ub4 + 1, 8);
        float gg = __shfl(tot, ub4 + 2, 8);
        float go = __shfl(tot, ub4 + 3, 8);
        float ii = sigmoid_f(gi);
        float ff = sigmoid_f(gf);
        float g  = tanh_f(gg);
        float oo = sigmoid_f(go);
        c = ff * c + ii * g;
        float h = oo * tanh_f(c);
        float hO = __shfl_xor(h, 4, 64);

        if (L == 0) {
            paircvt pk;
            pk.v.x = (_Float16)h;
            pk.v.y = (_Float16)hO;
            ((unsigned*)hs16)[(size_t)t * (HD / 2) + wid * 4 + w] = pk.u;
            const unsigned pout = (t + 1) & 1;
            const size_t slot = (size_t)wid * 4 + w;
            unsigned long long msg =
                ((unsigned long long)(t + 1) << 32) | (unsigned long long)pk.u;
            // authoritative publish (sc1, relays + fallbacks read this)
            __hip_atomic_store(&hmsg[(size_t)pout * NSLOT + slot], msg,
                               __ATOMIC_RELAXED, __HIP_MEMORY_SCOPE_AGENT);
            // local express copy for same-XCD consumers (plain store)
            mirr[((size_t)xcd * 2 + pout) * NSLOT + slot] = msg;
        }
    }
}

// Output projection: out[t,0:3] = hs[t]·W_uvw^T + b_uvw,
//                    out[t,3:6] = hs[t]·W_pqr^T + b_pqr
__global__ __launch_bounds__(256) void out_proj_kernel(
    const _Float16* __restrict__ hs16,
    const float* __restrict__ W_uvw, const float* __restrict__ b_uvw,
    const float* __restrict__ W_pqr, const float* __restrict__ b_pqr,
    float* __restrict__ out)
{
    __shared__ float Ws[6 * HD];
    const int tid = threadIdx.x;
    for (int i = tid; i < 3 * HD; i += 256) Ws[i] = W_uvw[i];
    for (int i = tid; i < 3 * HD; i += 256) Ws[3 * HD + i] = W_pqr[i];
    __syncthreads();

    const int w = tid >> 6, L = tid & 63;
#pragma unroll
    for (int r = 0; r < 4; ++r) {
        const int t = blockIdx.x * 16 + w * 4 + r;
        const _Float16* hrow = hs16 + (size_t)t * HD;
        float acc[6] = {0.f, 0.f, 0.f, 0.f, 0.f, 0.f};
        for (int cidx = L; cidx < HD; cidx += 64) {
            float hval = (float)hrow[cidx];
#pragma unroll
            for (int j = 0; j < 6; ++j) acc[j] += hval * Ws[j * HD + cidx];
        }
#pragma unroll
        for (int j = 0; j < 6; ++j) {
#pragma unroll
            for (int d = 1; d < 64; d <<= 1)
                acc[j] += __shfl_xor(acc[j], d, 64);
        }
        if (L == 0) {
#pragma unroll
            for (int j = 0; j < 6; ++j)
                out[(size_t)t * 6 + j] =
                    acc[j] + (j < 3 ? b_uvw[j] : b_pqr[j - 3]);
        }
    }
}

extern "C" void kernel_launch(void* const* d_in, const int* in_sizes, int n_in,
                              void* d_out, int out_size, void* d_ws, size_t ws_size,
                              hipStream_t stream) {
    (void)in_sizes; (void)n_in; (void)out_size; (void)ws_size;

    const float* sa    = (const float*)d_in[0];
    const float* W_ih  = (const float*)d_in[1];
    const float* W_hh  = (const float*)d_in[2];
    const float* b_ih  = (const float*)d_in[3];
    const float* b_hh  = (const float*)d_in[4];
    const float* W_uvw = (const float*)d_in[5];
    const float* b_uvw = (const float*)d_in[6];
    const float* W_pqr = (const float*)d_in[7];
    const float* b_pqr = (const float*)d_in[8];
    float* out = (float*)d_out;

    // workspace: [hs16: 32 MB][hmsg: 16 KB][mirr: 128 KB]
    char* ws = (char*)d_ws;
    _Float16* hs16 = (_Float16*)ws;
    unsigned long long* hmsg =
        (unsigned long long*)(ws + (size_t)SEQ * HD * 2);
    unsigned long long* mirr = hmsg + (size_t)2 * NSLOT;

    // zero comm area: tag 0 == "h_0 = 0 is ready" in global + all mirrors
    const size_t comm_bytes =
        (size_t)2 * NSLOT * 8 + (size_t)NXCD * 2 * NSLOT * 8;
    hipMemsetAsync(hmsg, 0, comm_bytes, stream);

    hipLaunchKernelGGL(lstm_persist, dim3(NGRID), dim3(NTHR), 0, stream,
                       sa, W_ih, W_hh, b_ih, b_hh, hmsg, mirr, hs16);
    hipLaunchKernelGGL(out_proj_kernel, dim3(SEQ / 16), dim3(256), 0, stream,
                       hs16, W_uvw, b_uvw, W_pqr, b_pqr, out);
}

// Round 9
// 19005.275 us; speedup vs baseline: 2.5149x; 1.1327x over previous
//
#include <hip/hip_runtime.h>
#include <cstdint>
#include <cstddef>

#define SEQ   8192
#define HD    2048
#define IND   16
#define NBLK  256   // one block per CU; each owns 8 hidden units
#define NTHR  256   // 4 waves; wave w owns units {b*8+2w, b*8+2w+1} = 8 rows
#define NSLOT 1024  // u64 slots per parity: lo32 = 2xfp16 h-pair, hi32 = tag
#define NXCD  8

typedef _Float16 h2  __attribute__((ext_vector_type(2)));
typedef unsigned u32x4 __attribute__((ext_vector_type(4)));

union paircvt { h2 v; unsigned u; };

__device__ __forceinline__ float fdot2f(h2 a, h2 b, float c) {
#if defined(__has_builtin)
#if __has_builtin(__builtin_amdgcn_fdot2)
    return __builtin_amdgcn_fdot2(a, b, c, false);
#else
    return c + (float)a.x * (float)b.x + (float)a.y * (float)b.y;
#endif
#else
    return c + (float)a.x * (float)b.x + (float)a.y * (float)b.y;
#endif
}

__device__ __forceinline__ float sigmoid_f(float x) {
    return 1.f / (1.f + __expf(-x));
}
__device__ __forceinline__ float tanh_f(float x) {
    float e = __expf(2.f * x);
    return 1.f - 2.f / (e + 1.f);
}

__device__ __forceinline__ unsigned my_xcd() {
    unsigned x;
    asm volatile("s_getreg_b32 %0, hwreg(HW_REG_XCC_ID, 0, 4)" : "=s"(x));
    return x & (NXCD - 1);
}

// Persistent LSTM, round 9: REPLICATED message arrays, no relay.
// R8's relay cut contention but added a serial hop (publish -> global ->
// relay -> mirror -> worker) and kept a shared-region fallback. Here the
// tagged-slot array is replicated 8x (one copy per XCD): each producer
// fire-and-forgets its 8B word into ALL copies (8 concurrent sc1 stores);
// each worker polls ONLY copy[my_xcd()] with sc1 (memory-side served,
// never stale). Minimum hops: publish flight + one poll discovery.
// Poll contention per line drops 8x (32 blocks/region) across 8 regions.
// Topology-safe by construction: every copy receives every slot, so XCD
// misidentification only affects load spreading, never correctness.
// Compute path = R5 verbatim (absmax 2.44e-4, 0 LDS conflicts, 1 barrier).
__global__ __launch_bounds__(NTHR, 1) void lstm_persist(
    const float* __restrict__ sa,    // [SEQ, IND]
    const float* __restrict__ W_ih,  // [4*HD, IND]
    const float* __restrict__ W_hh,  // [4*HD, HD]
    const float* __restrict__ b_ih,  // [4*HD]
    const float* __restrict__ b_hh,  // [4*HD]
    unsigned long long* __restrict__ hrep,  // [NXCD][2][NSLOT] replicas
    _Float16* __restrict__ hs16)     // [SEQ, HD] h history (fp16)
{
    const int b   = blockIdx.x;
    const int tid = threadIdx.x;
    const int w   = tid >> 6;        // wave 0..3
    const int L   = tid & 63;        // lane
    const unsigned xcd = my_xcd();

    __shared__ h2 hh2[16 * 64];      // h_t pairs, XOR-swizzled [k][row^2k]

    const int ubase = b * 8 + 2 * w; // first of this wave's 2 units

    // ---- one-time: W_hh fragment -> registers (fp16 pairs) ----
    // 8 rows (r: gate=r&3, unit=r>>2), lane L owns cols [32L, 32L+32)
    h2 wreg[8][16];
#pragma unroll
    for (int r = 0; r < 8; ++r) {
        const int row = (r & 3) * HD + ubase + (r >> 2);
        const float4* Wr = (const float4*)(W_hh + (size_t)row * HD + L * 32);
#pragma unroll
        for (int q = 0; q < 8; ++q) {
            float4 f = Wr[q];
            h2 lo; lo.x = (_Float16)f.x; lo.y = (_Float16)f.y;
            h2 hi; hi.x = (_Float16)f.z; hi.y = (_Float16)f.w;
            wreg[r][2 * q]     = lo;
            wreg[r][2 * q + 1] = hi;
        }
    }
    // W_ih row + bias for the row this lane ends up holding (r = L&7)
    const int rowL = (L & 3) * HD + ubase + ((L >> 2) & 1);
    float wih[IND];
    {
        const float4* Wi = (const float4*)(W_ih + (size_t)rowL * IND);
#pragma unroll
        for (int q = 0; q < 4; ++q) {
            float4 f = Wi[q];
            wih[4 * q]     = f.x;
            wih[4 * q + 1] = f.y;
            wih[4 * q + 2] = f.z;
            wih[4 * q + 3] = f.w;
        }
    }
    const float bias = b_ih[rowL] + b_hh[rowL];

    // cell state: lanes with (L&4)==0 hold c of unit0, (L&4)==4 -> unit1
    float c = 0.f;

    for (unsigned t = 0; t < SEQ; ++t) {
        // ---- xp precompute (h-independent): hidden under the poll ----
        float xp = bias;
        {
            const float* sat = sa + (size_t)t * IND;
#pragma unroll
            for (int k = 0; k < IND; ++k) xp += sat[k] * wih[k];
        }

        // ---- poll own-XCD replica (sc1: memory-side, never stale) ----
        const unsigned pin = t & 1;
        const uint32_t* base =
            (const uint32_t*)(hrep + ((size_t)xcd * 2 + pin) * NSLOT);
        const uint32_t* pp0 = base + 4 * tid;
        const uint32_t* pp1 = base + 1024 + 4 * tid;
        u32x4 m0, m1;
        for (;;) {
            asm volatile(
                "global_load_dwordx4 %0, %2, off sc1\n\t"
                "global_load_dwordx4 %1, %3, off sc1\n\t"
                "s_waitcnt vmcnt(0)"
                : "=v"(m0), "=v"(m1)
                : "v"(pp0), "v"(pp1) : "memory");
            bool ok = (m0.y == t) & (m0.w == t) & (m1.y == t) & (m1.w == t);
            if (ok) break;
            __builtin_amdgcn_s_sleep(1);
        }

        // ---- stage 4 pairs into swizzled LDS (<=2-way = free) ----
        {
            paircvt cv;
            const int pa = 2 * tid, pb = 2 * tid + 1;
            const int pc = 512 + 2 * tid, pd = 513 + 2 * tid;
            cv.u = m0.x;
            hh2[(pa & 15) * 64 + (((pa >> 4) ^ (2 * (pa & 15))) & 63)] = cv.v;
            cv.u = m0.z;
            hh2[(pb & 15) * 64 + (((pb >> 4) ^ (2 * (pb & 15))) & 63)] = cv.v;
            cv.u = m1.x;
            hh2[(pc & 15) * 64 + (((pc >> 4) ^ (2 * (pc & 15))) & 63)] = cv.v;
            cv.u = m1.z;
            hh2[(pd & 15) * 64 + (((pd >> 4) ^ (2 * (pd & 15))) & 63)] = cv.v;
        }
        __syncthreads();

        // ---- read this lane's 16 pairs (cols [32L, 32L+32)) ----
        h2 hv[16];
#pragma unroll
        for (int k = 0; k < 16; ++k)
            hv[k] = hh2[k * 64 + ((L ^ (2 * k)) & 63)];

        // ---- 8 rows x 32 cols of dot product per lane ----
        float p[8] = {0.f, 0.f, 0.f, 0.f, 0.f, 0.f, 0.f, 0.f};
#pragma unroll
        for (int r = 0; r < 8; ++r)
#pragma unroll
            for (int k = 0; k < 16; ++k)
                p[r] = fdot2f(wreg[r][k], hv[k], p[r]);

        // ---- merge-reduce: lane L ends with full sum of row (L&7) ----
        const bool h1 = (L & 1), h2b = (L & 2), h4 = (L & 4);
        float v0, v1, v2, v3;
        {
            float k0 = h1 ? p[1] : p[0], s0 = h1 ? p[0] : p[1];
            v0 = k0 + __shfl_xor(s0, 1, 64);
            float k1 = h1 ? p[3] : p[2], s1 = h1 ? p[2] : p[3];
            v1 = k1 + __shfl_xor(s1, 1, 64);
            float k2 = h1 ? p[5] : p[4], s2 = h1 ? p[4] : p[5];
            v2 = k2 + __shfl_xor(s2, 1, 64);
            float k3 = h1 ? p[7] : p[6], s3 = h1 ? p[6] : p[7];
            v3 = k3 + __shfl_xor(s3, 1, 64);
        }
        float w0, w1;
        {
            float k0 = h2b ? v1 : v0, s0 = h2b ? v0 : v1;
            w0 = k0 + __shfl_xor(s0, 2, 64);
            float k1 = h2b ? v3 : v2, s1 = h2b ? v2 : v3;
            w1 = k1 + __shfl_xor(s1, 2, 64);
        }
        float tot;
        {
            float k0 = h4 ? w1 : w0, s0 = h4 ? w0 : w1;
            tot = k0 + __shfl_xor(s0, 4, 64);
        }
        tot += __shfl_xor(tot, 8, 64);
        tot += __shfl_xor(tot, 16, 64);
        tot += __shfl_xor(tot, 32, 64);
        tot += xp;

        // ---- gates: all intra-wave (width-8 shuffles) ----
        const int ub4 = L & 4;   // 0 -> unit0 rows 0..3, 4 -> unit1 rows 4..7
        float gi = __shfl(tot, ub4 + 0, 8);
        float gf = __shfl(tot, ub4 + 1, 8);
        float gg = __shfl(tot, ub4 + 2, 8);
        float go = __shfl(tot, ub4 + 3, 8);
        float ii = sigmoid_f(gi);
        float ff = sigmoid_f(gf);
        float g  = tanh_f(gg);
        float oo = sigmoid_f(go);
        c = ff * c + ii * g;
        float h = oo * tanh_f(c);
        float hO = __shfl_xor(h, 4, 64);   // lane0: unit1's h (from lane4)

        // ---- publish: one 8B tagged word to ALL 8 replicas ----
        if (L == 0) {
            paircvt pk;
            pk.v.x = (_Float16)h;    // unit ubase
            pk.v.y = (_Float16)hO;   // unit ubase+1
            ((unsigned*)hs16)[(size_t)t * (HD / 2) + b * 4 + w] = pk.u;
            const unsigned pout = (t + 1) & 1;
            const size_t slot = (size_t)b * 4 + w;
            unsigned long long msg =
                ((unsigned long long)(t + 1) << 32) | (unsigned long long)pk.u;
#pragma unroll
            for (int x = 0; x < NXCD; ++x)
                __hip_atomic_store(
                    &hrep[((size_t)x * 2 + pout) * NSLOT + slot], msg,
                    __ATOMIC_RELAXED, __HIP_MEMORY_SCOPE_AGENT);
        }
    }
}

// Output projection: out[t,0:3] = hs[t]·W_uvw^T + b_uvw,
//                    out[t,3:6] = hs[t]·W_pqr^T + b_pqr
__global__ __launch_bounds__(256) void out_proj_kernel(
    const _Float16* __restrict__ hs16,
    const float* __restrict__ W_uvw, const float* __restrict__ b_uvw,
    const float* __restrict__ W_pqr, const float* __restrict__ b_pqr,
    float* __restrict__ out)
{
    __shared__ float Ws[6 * HD];
    const int tid = threadIdx.x;
    for (int i = tid; i < 3 * HD; i += 256) Ws[i] = W_uvw[i];
    for (int i = tid; i < 3 * HD; i += 256) Ws[3 * HD + i] = W_pqr[i];
    __syncthreads();

    const int w = tid >> 6, L = tid & 63;
#pragma unroll
    for (int r = 0; r < 4; ++r) {
        const int t = blockIdx.x * 16 + w * 4 + r;
        const _Float16* hrow = hs16 + (size_t)t * HD;
        float acc[6] = {0.f, 0.f, 0.f, 0.f, 0.f, 0.f};
        for (int cidx = L; cidx < HD; cidx += 64) {
            float hval = (float)hrow[cidx];
#pragma unroll
            for (int j = 0; j < 6; ++j) acc[j] += hval * Ws[j * HD + cidx];
        }
#pragma unroll
        for (int j = 0; j < 6; ++j) {
#pragma unroll
            for (int d = 1; d < 64; d <<= 1)
                acc[j] += __shfl_xor(acc[j], d, 64);
        }
        if (L == 0) {
#pragma unroll
            for (int j = 0; j < 6; ++j)
                out[(size_t)t * 6 + j] =
                    acc[j] + (j < 3 ? b_uvw[j] : b_pqr[j - 3]);
        }
    }
}

extern "C" void kernel_launch(void* const* d_in, const int* in_sizes, int n_in,
                              void* d_out, int out_size, void* d_ws, size_t ws_size,
                              hipStream_t stream) {
    (void)in_sizes; (void)n_in; (void)out_size; (void)ws_size;

    const float* sa    = (const float*)d_in[0];
    const float* W_ih  = (const float*)d_in[1];
    const float* W_hh  = (const float*)d_in[2];
    const float* b_ih  = (const float*)d_in[3];
    const float* b_hh  = (const float*)d_in[4];
    const float* W_uvw = (const float*)d_in[5];
    const float* b_uvw = (const float*)d_in[6];
    const float* W_pqr = (const float*)d_in[7];
    const float* b_pqr = (const float*)d_in[8];
    float* out = (float*)d_out;

    // workspace: [hs16: 32 MB][hrep: NXCD*2*NSLOT*8 = 128 KB]
    char* ws = (char*)d_ws;
    _Float16* hs16 = (_Float16*)ws;
    unsigned long long* hrep =
        (unsigned long long*)(ws + (size_t)SEQ * HD * 2);

    // zero replicas: tag 0 == "h_0 = 0 is ready" in every copy
    hipMemsetAsync(hrep, 0, (size_t)NXCD * 2 * NSLOT * 8, stream);

    hipLaunchKernelGGL(lstm_persist, dim3(NBLK), dim3(NTHR), 0, stream,
                       sa, W_ih, W_hh, b_ih, b_hh, hrep, hs16);
    hipLaunchKernelGGL(out_proj_kernel, dim3(SEQ / 16), dim3(256), 0, stream,
                       hs16, W_uvw, b_uvw, W_pqr, b_pqr, out);
}